// Round 4
// baseline (519.158 us; speedup 1.0000x reference)
//
#include <hip/hip_runtime.h>
#include <hip/hip_bf16.h>
#include <stdint.h>

// Problem constants
#define BATCH 16
#define SEQ   1024
#define HIDN  1024
#define NH    16
#define HD    64
#define PBSTRIDE 1025  // pos_bias last-dim stride (2*512+1)

typedef __attribute__((ext_vector_type(8))) short short8;
typedef __attribute__((ext_vector_type(4))) short short4v;
typedef __attribute__((ext_vector_type(4))) float f32x4;

__device__ __forceinline__ float bf2f(short x) {
    unsigned int u = ((unsigned int)(unsigned short)x) << 16;
    union { unsigned int u; float f; } c; c.u = u; return c.f;
}
__device__ __forceinline__ short f2bf(float f) {
    union { float f; unsigned int u; } c; c.f = f;
    unsigned int r = c.u + 0x7FFFu + ((c.u >> 16) & 1u);  // RNE
    return (short)(r >> 16);
}

typedef __attribute__((address_space(1))) void gvoid;
typedef __attribute__((address_space(3))) void svoid;
__device__ __forceinline__ void gload_lds16(const void* g, void* l) {
    __builtin_amdgcn_global_load_lds((gvoid*)g, (svoid*)l, 16, 0, 0);
}

// -------- dtype detector: fp32 normals have exponent field in [0x60,0x9F] --------
__global__ void detect_k(const unsigned int* __restrict__ hid_u, int* __restrict__ flag) {
    __shared__ int wsum[4];
    int t = threadIdx.x;
    int cnt = 0;
#pragma unroll
    for (int i = 0; i < 4; ++i) {
        unsigned int u = hid_u[t * 4 + i];
        unsigned int e = (u >> 23) & 0xFFu;
        if (e >= 0x60u && e <= 0x9Fu) cnt++;
    }
#pragma unroll
    for (int off = 1; off < 64; off <<= 1) cnt += __shfl_xor(cnt, off);
    if ((t & 63) == 0) wsum[t >> 6] = cnt;
    __syncthreads();
    if (t == 0) flag[0] = (wsum[0] + wsum[1] + wsum[2] + wsum[3] >= 512) ? 1 : 0;
}

// -------- diagnostic zero-fill: runs only when flag==0 (inputs NOT fp32) --------
__global__ void zerofill_k(short* __restrict__ out, const int* __restrict__ flag) {
    if (flag[0] != 0) return;
    long long i = ((long long)blockIdx.x * blockDim.x + threadIdx.x) * 8;
    short8 z = {};
    *(short8*)(out + i) = z;
}

// -------- weight conversion fp32 -> bf16 --------
__global__ void convw_k(const float* __restrict__ src, short* __restrict__ dst,
                        const int* __restrict__ flag) {
    if (flag[0] == 0) return;
    int i = (blockIdx.x * 256 + threadIdx.x) * 4;
    float4 f = *(const float4*)(src + i);
    short4v o;
    o[0] = f2bf(f.x); o[1] = f2bf(f.y); o[2] = f2bf(f.z); o[3] = f2bf(f.w);
    *(short4v*)(dst + i) = o;
}

// -------- posemb: hs_bf16 = fp32(hidden) + pos * W_pe + b_pe --------
__global__ void posemb_k(const float* __restrict__ hid, const float* __restrict__ wpe,
                         const float* __restrict__ bpe, short* __restrict__ hs,
                         const int* __restrict__ flag) {
    if (flag[0] == 0) return;
    long long idx = (long long)blockIdx.x * blockDim.x + threadIdx.x;
    long long base = idx * 8;
    int c = (int)(base & (HIDN - 1));
    int s = (int)((base >> 10) & (SEQ - 1));
    float pos = (float)(s - 512) * (1.0f / 512.0f);
    float4 h0 = *(const float4*)(hid + base);
    float4 h1 = *(const float4*)(hid + base + 4);
    float4 w0 = *(const float4*)(wpe + c);
    float4 w1 = *(const float4*)(wpe + c + 4);
    float4 b0 = *(const float4*)(bpe + c);
    float4 b1 = *(const float4*)(bpe + c + 4);
    short8 ov;
    ov[0] = f2bf(h0.x + pos * w0.x + b0.x);
    ov[1] = f2bf(h0.y + pos * w0.y + b0.y);
    ov[2] = f2bf(h0.z + pos * w0.z + b0.z);
    ov[3] = f2bf(h0.w + pos * w0.w + b0.w);
    ov[4] = f2bf(h1.x + pos * w1.x + b1.x);
    ov[5] = f2bf(h1.y + pos * w1.y + b1.y);
    ov[6] = f2bf(h1.z + pos * w1.z + b1.z);
    ov[7] = f2bf(h1.w + pos * w1.w + b1.w);
    *(short8*)(hs + base) = ov;
}

// -------- GEMM: C = A(bf16) @ W(bf16)^T + bias(fp32) --------
// M=16384, N=1024, K=1024. 128x128 tile, BK=32, 256 threads (4 waves 2x2).
// MODE 0: write fp32 C[m][n] row-major (out-proj). MODE 1: write bf16 [B,H,S,D].
template <int MODE>
__global__ __launch_bounds__(256) void gemm_nt(const short* __restrict__ A,
                                               const short* __restrict__ W,
                                               const float* __restrict__ bias,
                                               void* __restrict__ Cout,
                                               const int* __restrict__ flag) {
    if (flag[0] == 0) return;
    __shared__ __align__(16) short Als[128 * 32];
    __shared__ __align__(16) short Bls[128 * 32];
    const int tid  = threadIdx.x;
    const int lane = tid & 63;
    const int w    = tid >> 6;
    const int wr   = w >> 1, wc = w & 1;
    const int tm   = blockIdx.y * 128;
    const int tn   = blockIdx.x * 128;

    f32x4 acc[4][4] = {};

    const int srow = tid >> 2;            // 0..63
    const int skb  = (tid & 3) * 8;       // k sub-offset
    const long long a_base = (long long)(tm + srow) * 1024 + skb;
    const long long b_base = (long long)(tn + srow) * 1024 + skb;
    const int ldsw = w * 1024;            // wave-uniform LDS byte base

    const int fr = lane & 15;
    const int fg = (lane >> 4) * 8;

    for (int k0 = 0; k0 < 1024; k0 += 32) {
#pragma unroll
        for (int i = 0; i < 2; ++i) {
            gload_lds16((const void*)(A + a_base + (long long)i * 64 * 1024 + k0),
                        (void*)((char*)Als + i * 4096 + ldsw));
            gload_lds16((const void*)(W + b_base + (long long)i * 64 * 1024 + k0),
                        (void*)((char*)Bls + i * 4096 + ldsw));
        }
        __syncthreads();
        short8 af[4], bfr[4];
#pragma unroll
        for (int r = 0; r < 4; ++r) {
            af[r]  = *(const short8*)(Als + (wr * 64 + r * 16 + fr) * 32 + fg);
            bfr[r] = *(const short8*)(Bls + (wc * 64 + r * 16 + fr) * 32 + fg);
        }
#pragma unroll
        for (int mi = 0; mi < 4; ++mi)
#pragma unroll
            for (int ni = 0; ni < 4; ++ni)
                acc[mi][ni] = __builtin_amdgcn_mfma_f32_16x16x32_bf16(af[mi], bfr[ni], acc[mi][ni], 0, 0, 0);
        __syncthreads();
    }

    const int g4 = (lane >> 4) * 4;
#pragma unroll
    for (int ni = 0; ni < 4; ++ni) {
        int col = tn + wc * 64 + ni * 16 + fr;
        float bv = bias[col];
#pragma unroll
        for (int mi = 0; mi < 4; ++mi) {
#pragma unroll
            for (int r = 0; r < 4; ++r) {
                int row = tm + wr * 64 + mi * 16 + g4 + r;
                float val = acc[mi][ni][r] + bv;
                if (MODE == 0) {
                    ((float*)Cout)[(long long)row * 1024 + col] = val;
                } else {
                    int b = row >> 10, s = row & 1023;
                    int h = col >> 6, d = col & 63;
                    ((short*)Cout)[(((long long)(b * NH + h) * SEQ + s) << 6) + d] = f2bf(val);
                }
            }
        }
    }
}

// -------- attention (bf16 q/k/v internal, fp32 pos_bias) --------
// grid: x = q-tile (8), y = b*h (256). 256 threads = 4 waves, wave owns 32 q-rows.
__global__ __launch_bounds__(256) void attn_k(const short* __restrict__ Q,
                                              const short* __restrict__ Kg,
                                              const short* __restrict__ Vg,
                                              const float* __restrict__ pbias,
                                              short* __restrict__ ctx,
                                              const int* __restrict__ flag) {
    if (flag[0] == 0) return;
    __shared__ __align__(16) short Kls[128 * 72];       // K tile [key][d], pad 72
    __shared__ __align__(16) short Vls[64 * 136];       // V^T tile [d][key], pad 136
    __shared__ __align__(16) short Pls[4 * 32 * 136];   // per-wave P [qrow][key]

    const int tid  = threadIdx.x;
    const int lane = tid & 63;
    const int w    = tid >> 6;
    const int bh   = blockIdx.y;
    const int h    = bh & (NH - 1);
    const int qt   = blockIdx.x;
    const long long base = (long long)bh * (SEQ * HD);

    const int fr = lane & 15;
    const int fg = lane >> 4;

    short8 qf[2][2];
#pragma unroll
    for (int mi = 0; mi < 2; ++mi)
#pragma unroll
        for (int ks = 0; ks < 2; ++ks)
            qf[mi][ks] = *(const short8*)(Q + base + (long long)(qt * 128 + w * 32 + mi * 16 + fr) * HD + ks * 32 + fg * 8);

    f32x4 o[2][4] = {};
    float mrun[2][4], lrun[2][4];
#pragma unroll
    for (int mi = 0; mi < 2; ++mi)
#pragma unroll
        for (int r = 0; r < 4; ++r) { mrun[mi][r] = -1e30f; lrun[mi][r] = 0.0f; }

    short* Pw = Pls + w * 32 * 136;

    for (int kt = 0; kt < 8; ++kt) {
        __syncthreads();  // protect K/V LDS against previous iteration's reads
        {
            int rrow = tid >> 3;
            int dcol = (tid & 7) * 8;
#pragma unroll
            for (int i = 0; i < 4; ++i) {
                short8 kv = *(const short8*)(Kg + base + (long long)(kt * 128 + i * 32 + rrow) * HD + dcol);
                *(short8*)(Kls + (i * 32 + rrow) * 72 + dcol) = kv;
                short8 vv = *(const short8*)(Vg + base + (long long)(kt * 128 + i * 32 + rrow) * HD + dcol);
#pragma unroll
                for (int j = 0; j < 8; ++j)
                    Vls[(dcol + j) * 136 + i * 32 + rrow] = vv[j];
            }
        }
        __syncthreads();

        f32x4 sc[2][8] = {};
#pragma unroll
        for (int ks = 0; ks < 2; ++ks) {
#pragma unroll
            for (int ni = 0; ni < 8; ++ni) {
                short8 kb = *(const short8*)(Kls + (ni * 16 + fr) * 72 + ks * 32 + fg * 8);
#pragma unroll
                for (int mi = 0; mi < 2; ++mi)
                    sc[mi][ni] = __builtin_amdgcn_mfma_f32_16x16x32_bf16(qf[mi][ks], kb, sc[mi][ni], 0, 0, 0);
            }
        }

        float pb[8];
#pragma unroll
        for (int ni = 0; ni < 8; ++ni)
            pb[ni] = pbias[h * PBSTRIDE + kt * 128 + ni * 16 + fr];
#pragma unroll
        for (int mi = 0; mi < 2; ++mi)
#pragma unroll
            for (int ni = 0; ni < 8; ++ni)
#pragma unroll
                for (int r = 0; r < 4; ++r)
                    sc[mi][ni][r] = sc[mi][ni][r] * 0.125f + pb[ni];

#pragma unroll
        for (int mi = 0; mi < 2; ++mi) {
#pragma unroll
            for (int r = 0; r < 4; ++r) {
                float tmax = sc[mi][0][r];
#pragma unroll
                for (int ni = 1; ni < 8; ++ni) tmax = fmaxf(tmax, sc[mi][ni][r]);
#pragma unroll
                for (int off = 1; off < 16; off <<= 1)
                    tmax = fmaxf(tmax, __shfl_xor(tmax, off));
                float mnew = fmaxf(mrun[mi][r], tmax);
                float scl  = __expf(mrun[mi][r] - mnew);
                mrun[mi][r] = mnew;
                lrun[mi][r] *= scl;
#pragma unroll
                for (int di = 0; di < 4; ++di) o[mi][di][r] *= scl;
                float psum = 0.0f;
#pragma unroll
                for (int ni = 0; ni < 8; ++ni) {
                    float p = __expf(sc[mi][ni][r] - mnew);
                    sc[mi][ni][r] = p;
                    psum += p;
                }
#pragma unroll
                for (int off = 1; off < 16; off <<= 1)
                    psum += __shfl_xor(psum, off);
                lrun[mi][r] += psum;
            }
        }

#pragma unroll
        for (int mi = 0; mi < 2; ++mi)
#pragma unroll
            for (int ni = 0; ni < 8; ++ni)
#pragma unroll
                for (int r = 0; r < 4; ++r)
                    Pw[(mi * 16 + fg * 4 + r) * 136 + ni * 16 + fr] = f2bf(sc[mi][ni][r]);

#pragma unroll
        for (int ks = 0; ks < 4; ++ks) {
            short8 pa[2];
#pragma unroll
            for (int mi = 0; mi < 2; ++mi)
                pa[mi] = *(const short8*)(Pw + (mi * 16 + fr) * 136 + ks * 32 + fg * 8);
#pragma unroll
            for (int di = 0; di < 4; ++di) {
                short8 vb = *(const short8*)(Vls + (di * 16 + fr) * 136 + ks * 32 + fg * 8);
#pragma unroll
                for (int mi = 0; mi < 2; ++mi)
                    o[mi][di] = __builtin_amdgcn_mfma_f32_16x16x32_bf16(pa[mi], vb, o[mi][di], 0, 0, 0);
            }
        }
    }

    const int b = bh >> 4;
#pragma unroll
    for (int mi = 0; mi < 2; ++mi) {
#pragma unroll
        for (int r = 0; r < 4; ++r) {
            float inv = 1.0f / lrun[mi][r];
            int srow = qt * 128 + w * 32 + mi * 16 + fg * 4 + r;
#pragma unroll
            for (int di = 0; di < 4; ++di) {
                int d = di * 16 + fr;
                ctx[(long long)(b * SEQ + srow) * HIDN + h * HD + d] = f2bf(o[mi][di][r] * inv);
            }
        }
    }
}

// ---------------- launcher ----------------
extern "C" void kernel_launch(void* const* d_in, const int* in_sizes, int n_in,
                              void* d_out, int out_size, void* d_ws, size_t ws_size,
                              hipStream_t stream) {
    const float* hid  = (const float*)d_in[0];
    const float* Wq   = (const float*)d_in[1];
    const float* bq   = (const float*)d_in[2];
    const float* Wk   = (const float*)d_in[3];
    const float* bk   = (const float*)d_in[4];
    const float* Wv   = (const float*)d_in[5];
    const float* bv   = (const float*)d_in[6];
    const float* Wo   = (const float*)d_in[7];
    const float* bo   = (const float*)d_in[8];
    const float* Wpe  = (const float*)d_in[9];
    const float* bpe  = (const float*)d_in[10];
    const float* pbias = (const float*)d_in[11];

    const long long NE = (long long)BATCH * SEQ * HIDN;  // 16M elements
    const long long WSZ = (long long)HIDN * HIDN;        // 1M elements per weight

    // ws (shorts): hs [0,NE) | v [NE,2NE) | Wc_q/k/v/o [2NE, 2NE+4*WSZ) | flag
    short* hs   = (short*)d_ws;
    short* v    = hs + NE;
    short* Wcq  = v + NE;
    short* Wck  = Wcq + WSZ;
    short* Wcv  = Wck + WSZ;
    short* Wco  = Wcv + WSZ;
    int*   flag = (int*)(Wco + WSZ);
    // d_out (fp32, 2*NE shorts worth): q [0,NE) | k [NE,2NE)
    short* q    = (short*)d_out;
    short* k    = q + NE;
    short* ctx  = hs;  // alias: hs dead after QKV projections

    detect_k<<<1, 256, 0, stream>>>((const unsigned int*)hid, flag);
    zerofill_k<<<(int)(NE / 8 / 256), 256, 0, stream>>>((short*)d_out, flag);

    posemb_k<<<(int)(NE / 8 / 256), 256, 0, stream>>>(hid, Wpe, bpe, hs, flag);
    convw_k<<<(int)(WSZ / 4 / 256), 256, 0, stream>>>(Wq, Wcq, flag);
    convw_k<<<(int)(WSZ / 4 / 256), 256, 0, stream>>>(Wk, Wck, flag);
    convw_k<<<(int)(WSZ / 4 / 256), 256, 0, stream>>>(Wv, Wcv, flag);
    convw_k<<<(int)(WSZ / 4 / 256), 256, 0, stream>>>(Wo, Wco, flag);

    dim3 gg(8, 128);  // N tiles x M tiles
    gemm_nt<1><<<gg, 256, 0, stream>>>(hs, Wcq, bq, q, flag);
    gemm_nt<1><<<gg, 256, 0, stream>>>(hs, Wck, bk, k, flag);
    gemm_nt<1><<<gg, 256, 0, stream>>>(hs, Wcv, bv, v, flag);

    attn_k<<<dim3(8, 256), 256, 0, stream>>>(q, k, v, pbias, ctx, flag);

    gemm_nt<0><<<gg, 256, 0, stream>>>(ctx, Wco, bo, d_out, flag);
}